// Round 1
// baseline (600.393 us; speedup 1.0000x reference)
//
#include <hip/hip_runtime.h>

// Problem: T=8, N=256, F=128. All inputs/outputs FLOAT32 (per reference).
// Decomposition: y[t,i,j,f] = A[t,i,f] + B[t,j,f],
//   A = x @ w[:, :F]^T, B = x @ w[:, F:]^T   (per branch).
// BN train-mode stats decompose onto A/B:
//   mean = (SA+SB)/(T*N),  E[y^2] = (QA+QB)/(T*N) + 2*sum_t SA_t.SB_t/(T*N^2)
// Final kernel streams 537 MB of f32 output (write-roofline ~110 us).
//
// R1 change vs 584us baseline: k_edge no longer does a 64-lane butterfly
// (6x ds_bpermute + lgkmcnt waits per 512B row = serialized chain that held
// writes to ~0.94 TB/s). Denominators are precomputed per-block into LDS
// (phase 1, zero shuffles), then phase 2 is a pure 16B/lane nontemporal
// stream with no cross-lane ops.

#define TT 8
#define NN 256
#define FF 128
// rows = T*N = 2048; per-array ws region = 2048*128 = 262144 floats

typedef float vf4 __attribute__((ext_vector_type(4)));

// ---------------------------------------------------------------------------
// Kernel 1: A1,B1,A2,B2 [2048 rows][128 f] from f32 x and w1/w2.
// 512 blocks x 128 threads; block = 4 rows; thread = output channel f.
// ---------------------------------------------------------------------------
__global__ __launch_bounds__(128) void k_matmul(
    const float* __restrict__ x,    // [2048][128]
    const float* __restrict__ w1,   // [128][256]
    const float* __restrict__ w2,   // [128][256]
    float* __restrict__ ws)
{
    __shared__ float xs[4][FF];
    const int tid = threadIdx.x;
    const int row0 = blockIdx.x * 4;

    // stage 4 x-rows into LDS: 512 floats = 128 float4, one per thread
    {
        const float4* xv = (const float4*)(x + row0 * FF);
        float4 q = xv[tid];
        ((float4*)&xs[0][0])[tid] = q;
    }
    __syncthreads();

    const int f = tid;
    float acc0[4] = {0,0,0,0}, acc1[4] = {0,0,0,0};
    float acc2[4] = {0,0,0,0}, acc3[4] = {0,0,0,0};
    const float4* w1v = (const float4*)w1;  // row f = 64 float4 (32 A-half, 32 B-half)
    const float4* w2v = (const float4*)w2;

    #pragma unroll 8
    for (int c4 = 0; c4 < 32; ++c4) {
        float4 qa1 = w1v[f * 64 + c4];
        float4 qb1 = w1v[f * 64 + 32 + c4];
        float4 qa2 = w2v[f * 64 + c4];
        float4 qb2 = w2v[f * 64 + 32 + c4];
        const int c = c4 * 4;
        #pragma unroll
        for (int r = 0; r < 4; ++r) {
            float x0 = xs[r][c], x1 = xs[r][c + 1], x2 = xs[r][c + 2], x3 = xs[r][c + 3];
            acc0[r] = fmaf(x0, qa1.x, fmaf(x1, qa1.y, fmaf(x2, qa1.z, fmaf(x3, qa1.w, acc0[r]))));
            acc1[r] = fmaf(x0, qb1.x, fmaf(x1, qb1.y, fmaf(x2, qb1.z, fmaf(x3, qb1.w, acc1[r]))));
            acc2[r] = fmaf(x0, qa2.x, fmaf(x1, qa2.y, fmaf(x2, qa2.z, fmaf(x3, qa2.w, acc2[r]))));
            acc3[r] = fmaf(x0, qb2.x, fmaf(x1, qb2.y, fmaf(x2, qb2.z, fmaf(x3, qb2.w, acc3[r]))));
        }
    }

    float* A1 = ws;
    float* B1 = ws + 262144;
    float* A2 = ws + 524288;
    float* B2 = ws + 786432;
    #pragma unroll
    for (int r = 0; r < 4; ++r) {
        int row = row0 + r;
        A1[row * FF + f] = acc0[r];
        B1[row * FF + f] = acc1[r];
        A2[row * FF + f] = acc2[r];
        B2[row * FF + f] = acc3[r];
    }
}

// ---------------------------------------------------------------------------
// Kernel 2a: per-(array, t) channel sums and sum-of-squares over n.
// grid = 32 (t in [0,8) x arr in [0,4)), block = 256.
// ---------------------------------------------------------------------------
__global__ __launch_bounds__(256) void k_stats(
    const float* __restrict__ ab,
    float* __restrict__ sums, float* __restrict__ sumsq)
{
    const int bx = blockIdx.x;
    const int t = bx & 7, arr = bx >> 3;
    const float* A = ab + arr * 262144 + t * NN * FF;
    const int tid = threadIdx.x;
    const int f = tid & 127, h = tid >> 7;
    float s = 0.f, q = 0.f;
    for (int n = h; n < NN; n += 2) {
        float v = A[n * FF + f];
        s += v;
        q = fmaf(v, v, q);
    }
    __shared__ float ls[256], lq[256];
    ls[tid] = s; lq[tid] = q;
    __syncthreads();
    if (tid < 128) {
        sums [(arr * 8 + t) * FF + f] = ls[tid] + ls[tid + 128];
        sumsq[(arr * 8 + t) * FF + f] = lq[tid] + lq[tid + 128];
    }
}

// ---------------------------------------------------------------------------
// Kernel 2b: fold BN (train-mode, biased var) into per-channel scale/bias.
// 1 block x 256 threads (branch = tid>>7, f = tid&127).
// ---------------------------------------------------------------------------
__global__ __launch_bounds__(256) void k_scale(
    const float* __restrict__ sums, const float* __restrict__ sumsq,
    const float* __restrict__ g1, const float* __restrict__ b1,
    const float* __restrict__ g2, const float* __restrict__ b2,
    float* __restrict__ scale, float* __restrict__ bias)
{
    const int tid = threadIdx.x;
    const int br = tid >> 7, f = tid & 127;
    const int aA = 2 * br, aB = 2 * br + 1;
    float SA = 0.f, SB = 0.f, QA = 0.f, QB = 0.f, cross = 0.f;
    #pragma unroll
    for (int t = 0; t < TT; ++t) {
        float sa = sums[(aA * 8 + t) * FF + f];
        float sb = sums[(aB * 8 + t) * FF + f];
        SA += sa; SB += sb;
        cross = fmaf(sa, sb, cross);
        QA += sumsq[(aA * 8 + t) * FF + f];
        QB += sumsq[(aB * 8 + t) * FF + f];
    }
    const float invTN  = 1.0f / 2048.0f;    // 1/(T*N)
    const float invTNN = 1.0f / 262144.0f;  // 2/(T*N*N)
    float mA = SA * invTN, mB = SB * invTN;
    float m = mA + mB;
    float ey2 = (QA + QB) * invTN + cross * invTNN;
    float var = ey2 - m * m;
    float gf = br ? g2[f] : g1[f];
    float bf = br ? b2[f] : b1[f];
    float sc = gf * rsqrtf(var + 1e-5f);
    scale[br * FF + f] = sc;
    bias [br * FF + f] = bf - m * sc;
}

// ---------------------------------------------------------------------------
// Kernel 4: the streaming kernel, shuffle-free.
// One block per output row-panel (t,br,i): 256 threads.
//   Phase 0: stage s[f] and c[f] = s[f]*A[i,f]+bias[f] into LDS.
//   Phase 1: thread j privately reduces l1 over f (32x float4, no shuffles)
//            -> r_lds[j] = 1/max(l1, eps).
//   Phase 2: pure stream. Wave w covers j in [64w,64w+64), 2 rows/iter;
//            lane holds 4 channels (16B load + 16B nontemporal store,
//            1 KB contiguous per instruction). Diagonal folds into r.
// ---------------------------------------------------------------------------
__global__ __launch_bounds__(256) void k_edge(
    const float* __restrict__ ws,
    const float* __restrict__ scale, const float* __restrict__ bias,
    float* __restrict__ out)
{
    const int bx = blockIdx.x;
    const int i  = bx & 255;
    const int br = (bx >> 8) & 1;
    const int t  = bx >> 9;
    const int tid = threadIdx.x;

    const float* A = ws + (2 * br) * 262144 + (t * NN + i) * FF;
    const float* B = ws + (2 * br + 1) * 262144 + t * NN * FF;

    __shared__ vf4 sc_lds[FF / 4];   // scale[f]
    __shared__ vf4 cc_lds[FF / 4];   // c[f] = s[f]*A[i,f] + bias[f]
    __shared__ float r_lds[NN];      // 1/l1 per row j

    // phase 0
    if (tid < FF) {
        float sf = scale[br * FF + tid];
        float cf = fmaf(A[tid], sf, bias[br * FF + tid]);
        ((float*)sc_lds)[tid] = sf;
        ((float*)cc_lds)[tid] = cf;
    }
    __syncthreads();

    // phase 1: thread j reduces its own row — no cross-lane ops
    {
        const vf4* Bj = (const vf4*)(B + tid * FF);
        float sum = 0.f;
        #pragma unroll 8
        for (int f4 = 0; f4 < FF / 4; ++f4) {
            vf4 b = Bj[f4];
            vf4 s = sc_lds[f4];
            vf4 c = cc_lds[f4];
            sum += fmaxf(fmaf(b.x, s.x, c.x), 0.f)
                 + fmaxf(fmaf(b.y, s.y, c.y), 0.f)
                 + fmaxf(fmaf(b.z, s.z, c.z), 0.f)
                 + fmaxf(fmaf(b.w, s.w, c.w), 0.f);
        }
        r_lds[tid] = 1.0f / fmaxf(sum, 1e-12f);
    }
    __syncthreads();

    // phase 2: pure stream
    const int wave = tid >> 6, lane = tid & 63;
    const int fo = (lane & 31) * 4;   // channel offset (4 ch/lane)
    const int jh = lane >> 5;         // which row of the pair

    const vf4 s4 = *(const vf4*)((const float*)sc_lds + fo);
    const vf4 c4 = *(const vf4*)((const float*)cc_lds + fo);

    vf4* obase = (vf4*)(out + ((size_t)(t * 2 + br) * NN + i) * (size_t)NN * FF);

    #pragma unroll 4
    for (int jj = 0; jj < 32; ++jj) {
        const int j = wave * 64 + jj * 2 + jh;
        vf4 b = *(const vf4*)(B + j * FF + fo);
        float r = r_lds[j];
        r = (j == i) ? 0.0f : r;   // zeroed diagonal folds into r
        vf4 v;
        v.x = fmaxf(fmaf(b.x, s4.x, c4.x), 0.f) * r;
        v.y = fmaxf(fmaf(b.y, s4.y, c4.y), 0.f) * r;
        v.z = fmaxf(fmaf(b.z, s4.z, c4.z), 0.f) * r;
        v.w = fmaxf(fmaf(b.w, s4.w, c4.w), 0.f) * r;
        __builtin_nontemporal_store(v, &obase[(size_t)j * 32 + (lane & 31)]);
    }
}

// ---------------------------------------------------------------------------
extern "C" void kernel_launch(void* const* d_in, const int* in_sizes, int n_in,
                              void* d_out, int out_size, void* d_ws, size_t ws_size,
                              hipStream_t stream)
{
    const float* x  = (const float*)d_in[0];   // node_feats f32 [8,256,128]
    const float* w1 = (const float*)d_in[1];   // w1 f32 [128,256]
    const float* g1 = (const float*)d_in[2];
    const float* b1 = (const float*)d_in[3];
    const float* w2 = (const float*)d_in[4];
    const float* g2 = (const float*)d_in[5];
    const float* b2 = (const float*)d_in[6];

    float* ws    = (float*)d_ws;           // A1,B1,A2,B2: 4 x 262144 floats
    float* sums  = ws + 1048576;           // [4][8][128]
    float* sumsq = sums + 4096;            // [4][8][128]
    float* scale = sumsq + 4096;           // [2][128]
    float* bias  = scale + 256;            // [2][128]
    float* out = (float*)d_out;

    k_matmul<<<512, 128, 0, stream>>>(x, w1, w2, ws);
    k_stats <<<32, 256, 0, stream>>>(ws, sums, sumsq);
    k_scale <<<1, 256, 0, stream>>>(sums, sumsq, g1, b1, g2, b2, scale, bias);
    k_edge  <<<4096, 256, 0, stream>>>(ws, scale, bias, out);
}

// Round 2
// 572.627 us; speedup vs baseline: 1.0485x; 1.0485x over previous
//
#include <hip/hip_runtime.h>

// Problem: T=8, N=256, F=128. All inputs/outputs FLOAT32 (per reference).
// Decomposition: y[t,i,j,f] = A[t,i,f] + B[t,j,f],
//   A = x @ w[:, :F]^T, B = x @ w[:, F:]^T   (per branch).
// BN train-mode stats decompose onto A/B:
//   mean = (SA+SB)/(T*N),  E[y^2] = (QA+QB)/(T*N) + 2*sum_t SA_t.SB_t/(T*N^2)
// Final kernel streams 537 MB of f32 output (write-roofline ~90-110 us).
//
// R2 change vs R1 (600us, neutral vs 584 baseline): R1's k_edge phase 1
// (per-row L1 denominators) read B with 512B lane stride -> every wave load
// fragmented into 64 requests (8192 req/block), same serialized cost as the
// old shuffle chain. R2 adds a transposed copy Bt[f][j] (written for free
// from k_matmul's accumulators) so phase 1 is fully coalesced float4 loads
// (64x fewer requests), combined via a tiny 2-stage LDS reduction.
// k_matmul widened to 8 rows/block (256 blocks): half the redundant w-reads.

#define TT 8
#define NN 256
#define FF 128
// rows = T*N = 2048; per-array ws region = 2048*128 = 262144 floats
// ws layout (floats):
//   A1:0  B1:262144  A2:524288  B2:786432
//   B1t:1048576  B2t:1310720          (each [8 t][128 f][256 j])
//   sums:1572864[4096] sumsq:1576960[4096] scale:1581056[256] bias:1581312[256]

typedef float vf4 __attribute__((ext_vector_type(4)));

// ---------------------------------------------------------------------------
// Kernel 1: A1,B1,A2,B2 [2048 rows][128 f] (+ transposed B1t,B2t) from x, w.
// 256 blocks x 128 threads; block = 8 rows; thread = output channel f.
// ---------------------------------------------------------------------------
__global__ __launch_bounds__(128) void k_matmul(
    const float* __restrict__ x,    // [2048][128]
    const float* __restrict__ w1,   // [128][256]
    const float* __restrict__ w2,   // [128][256]
    float* __restrict__ ws)
{
    __shared__ float xs[8][FF];
    const int tid = threadIdx.x;
    const int row0 = blockIdx.x * 8;

    // stage 8 x-rows into LDS: 1024 floats = 256 float4, two per thread
    {
        const float4* xv = (const float4*)(x + row0 * FF);
        ((float4*)xs)[tid]       = xv[tid];
        ((float4*)xs)[tid + 128] = xv[tid + 128];
    }
    __syncthreads();

    const int f = tid;
    float acc0[8], acc1[8], acc2[8], acc3[8];
    #pragma unroll
    for (int r = 0; r < 8; ++r) { acc0[r]=0.f; acc1[r]=0.f; acc2[r]=0.f; acc3[r]=0.f; }

    const float4* w1v = (const float4*)w1;  // row f = 64 float4 (32 A-half, 32 B-half)
    const float4* w2v = (const float4*)w2;

    #pragma unroll 4
    for (int c4 = 0; c4 < 32; ++c4) {
        float4 qa1 = w1v[f * 64 + c4];
        float4 qb1 = w1v[f * 64 + 32 + c4];
        float4 qa2 = w2v[f * 64 + c4];
        float4 qb2 = w2v[f * 64 + 32 + c4];
        const int c = c4 * 4;
        #pragma unroll
        for (int r = 0; r < 8; ++r) {
            float x0 = xs[r][c], x1 = xs[r][c + 1], x2 = xs[r][c + 2], x3 = xs[r][c + 3];
            acc0[r] = fmaf(x0, qa1.x, fmaf(x1, qa1.y, fmaf(x2, qa1.z, fmaf(x3, qa1.w, acc0[r]))));
            acc1[r] = fmaf(x0, qb1.x, fmaf(x1, qb1.y, fmaf(x2, qb1.z, fmaf(x3, qb1.w, acc1[r]))));
            acc2[r] = fmaf(x0, qa2.x, fmaf(x1, qa2.y, fmaf(x2, qa2.z, fmaf(x3, qa2.w, acc2[r]))));
            acc3[r] = fmaf(x0, qb2.x, fmaf(x1, qb2.y, fmaf(x2, qb2.z, fmaf(x3, qb2.w, acc3[r]))));
        }
    }

    float* A1 = ws;
    float* B1 = ws + 262144;
    float* A2 = ws + 524288;
    float* B2 = ws + 786432;
    #pragma unroll
    for (int r = 0; r < 8; ++r) {
        int row = row0 + r;
        A1[row * FF + f] = acc0[r];
        B1[row * FF + f] = acc1[r];
        A2[row * FF + f] = acc2[r];
        B2[row * FF + f] = acc3[r];
    }

    // transposed B copies: thread f holds B[row0..row0+7][f] in acc1/acc3
    // Bt layout per array: [t][f][256 j]; all 8 rows of a block share one t.
    {
        const int t  = row0 >> 8;
        const int n0 = row0 & 255;
        float* b1t = ws + 1048576 + (t * FF + f) * NN + n0;
        float* b2t = ws + 1310720 + (t * FF + f) * NN + n0;
        vf4 p0 = {acc1[0], acc1[1], acc1[2], acc1[3]};
        vf4 p1 = {acc1[4], acc1[5], acc1[6], acc1[7]};
        vf4 q0 = {acc3[0], acc3[1], acc3[2], acc3[3]};
        vf4 q1 = {acc3[4], acc3[5], acc3[6], acc3[7]};
        *(vf4*)(b1t)     = p0;
        *(vf4*)(b1t + 4) = p1;
        *(vf4*)(b2t)     = q0;
        *(vf4*)(b2t + 4) = q1;
    }
}

// ---------------------------------------------------------------------------
// Kernel 2a: per-(array, t) channel sums and sum-of-squares over n.
// grid = 32 (t in [0,8) x arr in [0,4)), block = 256.
// ---------------------------------------------------------------------------
__global__ __launch_bounds__(256) void k_stats(
    const float* __restrict__ ab,
    float* __restrict__ sums, float* __restrict__ sumsq)
{
    const int bx = blockIdx.x;
    const int t = bx & 7, arr = bx >> 3;
    const float* A = ab + arr * 262144 + t * NN * FF;
    const int tid = threadIdx.x;
    const int f = tid & 127, h = tid >> 7;
    float s = 0.f, q = 0.f;
    for (int n = h; n < NN; n += 2) {
        float v = A[n * FF + f];
        s += v;
        q = fmaf(v, v, q);
    }
    __shared__ float ls[256], lq[256];
    ls[tid] = s; lq[tid] = q;
    __syncthreads();
    if (tid < 128) {
        sums [(arr * 8 + t) * FF + f] = ls[tid] + ls[tid + 128];
        sumsq[(arr * 8 + t) * FF + f] = lq[tid] + lq[tid + 128];
    }
}

// ---------------------------------------------------------------------------
// Kernel 2b: fold BN (train-mode, biased var) into per-channel scale/bias.
// 1 block x 256 threads (branch = tid>>7, f = tid&127).
// ---------------------------------------------------------------------------
__global__ __launch_bounds__(256) void k_scale(
    const float* __restrict__ sums, const float* __restrict__ sumsq,
    const float* __restrict__ g1, const float* __restrict__ b1,
    const float* __restrict__ g2, const float* __restrict__ b2,
    float* __restrict__ scale, float* __restrict__ bias)
{
    const int tid = threadIdx.x;
    const int br = tid >> 7, f = tid & 127;
    const int aA = 2 * br, aB = 2 * br + 1;
    float SA = 0.f, SB = 0.f, QA = 0.f, QB = 0.f, cross = 0.f;
    #pragma unroll
    for (int t = 0; t < TT; ++t) {
        float sa = sums[(aA * 8 + t) * FF + f];
        float sb = sums[(aB * 8 + t) * FF + f];
        SA += sa; SB += sb;
        cross = fmaf(sa, sb, cross);
        QA += sumsq[(aA * 8 + t) * FF + f];
        QB += sumsq[(aB * 8 + t) * FF + f];
    }
    const float invTN  = 1.0f / 2048.0f;    // 1/(T*N)
    const float invTNN = 1.0f / 262144.0f;  // 2/(T*N*N)
    float mA = SA * invTN, mB = SB * invTN;
    float m = mA + mB;
    float ey2 = (QA + QB) * invTN + cross * invTNN;
    float var = ey2 - m * m;
    float gf = br ? g2[f] : g1[f];
    float bf = br ? b2[f] : b1[f];
    float sc = gf * rsqrtf(var + 1e-5f);
    scale[br * FF + f] = sc;
    bias [br * FF + f] = bf - m * sc;
}

// ---------------------------------------------------------------------------
// Kernel 4: the streaming kernel, shuffle-free, fully coalesced.
// One block per output row-panel (t,br,i): 256 threads.
//   Phase 0: stage s[f] and c[f] = s[f]*A[i,f]+bias[f] into LDS.
//   Phase 1: L1 denominators from TRANSPOSED Bt[f][j]: thread (fq,jq) sums
//            its f-quarter for a j-quad via coalesced vf4 loads (1KB/instr),
//            then a 2-stage LDS combine -> r_lds[j] = 1/max(l1,eps).
//   Phase 2: pure stream. Wave w covers j in [64w,64w+64), 2 rows/iter;
//            16B/lane load + 16B/lane nontemporal store (1 KB contiguous).
// ---------------------------------------------------------------------------
__global__ __launch_bounds__(256) void k_edge(
    const float* __restrict__ ws,
    const float* __restrict__ scale, const float* __restrict__ bias,
    float* __restrict__ out)
{
    const int bx = blockIdx.x;
    const int i  = bx & 255;
    const int br = (bx >> 8) & 1;
    const int t  = bx >> 9;
    const int tid = threadIdx.x;

    const float* A  = ws + (2 * br) * 262144 + (t * NN + i) * FF;
    const float* B  = ws + (2 * br + 1) * 262144 + t * NN * FF;
    const float* Bt = ws + 1048576 + br * 262144 + t * FF * NN;  // [128 f][256 j]

    __shared__ float sc_lds[FF];
    __shared__ float cc_lds[FF];
    __shared__ vf4   part[4][NN / 4];  // per-f-quarter partial L1 sums
    __shared__ float r_lds[NN];        // 1/l1 per row j

    // phase 0
    if (tid < FF) {
        float sf = scale[br * FF + tid];
        float cf = fmaf(A[tid], sf, bias[br * FF + tid]);
        sc_lds[tid] = sf;
        cc_lds[tid] = cf;
    }
    __syncthreads();

    // phase 1: coalesced denominator pass over Bt
    {
        const int jq = tid & 63;    // j-quad: j = 4*jq .. 4*jq+3
        const int fq = tid >> 6;    // f-quarter: f = 32*fq .. 32*fq+31
        const float* bt = Bt + (fq * 32) * NN + jq * 4;
        float s0 = 0.f, s1 = 0.f, s2 = 0.f, s3 = 0.f;
        #pragma unroll 8
        for (int ff = 0; ff < 32; ++ff) {
            vf4 b = *(const vf4*)(bt + ff * NN);
            const int f = fq * 32 + ff;
            float sf = sc_lds[f];   // wave-uniform -> LDS broadcast
            float cf = cc_lds[f];
            s0 += fmaxf(fmaf(b.x, sf, cf), 0.f);
            s1 += fmaxf(fmaf(b.y, sf, cf), 0.f);
            s2 += fmaxf(fmaf(b.z, sf, cf), 0.f);
            s3 += fmaxf(fmaf(b.w, sf, cf), 0.f);
        }
        vf4 p = {s0, s1, s2, s3};
        part[fq][jq] = p;
    }
    __syncthreads();
    {
        // combine the 4 f-quarter partials for row j = tid
        const float* p0 = (const float*)&part[0][0];
        const float* p1 = (const float*)&part[1][0];
        const float* p2 = (const float*)&part[2][0];
        const float* p3 = (const float*)&part[3][0];
        float l1 = p0[tid] + p1[tid] + p2[tid] + p3[tid];
        r_lds[tid] = 1.0f / fmaxf(l1, 1e-12f);
    }
    __syncthreads();

    // phase 2: pure stream
    const int wave = tid >> 6, lane = tid & 63;
    const int fo = (lane & 31) * 4;   // channel offset (4 ch/lane)
    const int jh = lane >> 5;         // which row of the pair

    const vf4 s4 = *(const vf4*)(sc_lds + fo);
    const vf4 c4 = *(const vf4*)(cc_lds + fo);

    vf4* obase = (vf4*)(out + ((size_t)(t * 2 + br) * NN + i) * (size_t)NN * FF);

    #pragma unroll 4
    for (int jj = 0; jj < 32; ++jj) {
        const int j = wave * 64 + jj * 2 + jh;
        vf4 b = *(const vf4*)(B + j * FF + fo);
        float r = r_lds[j];
        r = (j == i) ? 0.0f : r;   // zeroed diagonal folds into r
        vf4 v;
        v.x = fmaxf(fmaf(b.x, s4.x, c4.x), 0.f) * r;
        v.y = fmaxf(fmaf(b.y, s4.y, c4.y), 0.f) * r;
        v.z = fmaxf(fmaf(b.z, s4.z, c4.z), 0.f) * r;
        v.w = fmaxf(fmaf(b.w, s4.w, c4.w), 0.f) * r;
        __builtin_nontemporal_store(v, &obase[(size_t)j * 32 + (lane & 31)]);
    }
}

// ---------------------------------------------------------------------------
extern "C" void kernel_launch(void* const* d_in, const int* in_sizes, int n_in,
                              void* d_out, int out_size, void* d_ws, size_t ws_size,
                              hipStream_t stream)
{
    const float* x  = (const float*)d_in[0];   // node_feats f32 [8,256,128]
    const float* w1 = (const float*)d_in[1];   // w1 f32 [128,256]
    const float* g1 = (const float*)d_in[2];
    const float* b1 = (const float*)d_in[3];
    const float* w2 = (const float*)d_in[4];
    const float* g2 = (const float*)d_in[5];
    const float* b2 = (const float*)d_in[6];

    float* ws    = (float*)d_ws;            // A1,B1,A2,B2 + B1t,B2t
    float* sums  = ws + 1572864;            // [4][8][128]
    float* sumsq = sums + 4096;             // [4][8][128]
    float* scale = sumsq + 4096;            // [2][128]
    float* bias  = scale + 256;             // [2][128]
    float* out = (float*)d_out;

    k_matmul<<<256, 128, 0, stream>>>(x, w1, w2, ws);
    k_stats <<<32, 256, 0, stream>>>(ws, sums, sumsq);
    k_scale <<<1, 256, 0, stream>>>(sums, sumsq, g1, b1, g2, b2, scale, bias);
    k_edge  <<<4096, 256, 0, stream>>>(ws, scale, bias, out);
}